// Round 1
// baseline (1270.093 us; speedup 1.0000x reference)
//
#include <hip/hip_runtime.h>
#include <hip/hip_fp16.h>

// Problem constants (fixed by the reference file)
#define M_DIM 16384   // B*S = 4*4096
#define N_DIM 4096    // DOUT
#define K_DIM 4096    // DIN

typedef __attribute__((ext_vector_type(4))) float f32x4;

// ---------------------------------------------------------------------------
// Quantization: fp32 (fp16-exact values) -> fp8, RNE via hardware cvt_pk.
// E4M3=true  -> OCP e4m3fn  (weight)
// E4M3=false -> OCP e5m2    (activations)
// Each thread handles 8 elements: 32B in, 8B out.
// ---------------------------------------------------------------------------
template<bool E4M3>
__global__ __launch_bounds__(256) void quant_kernel(const float* __restrict__ in,
                                                    uint2* __restrict__ out,
                                                    int n8) {
  int i = blockIdx.x * 256 + threadIdx.x;
  if (i >= n8) return;
  const float4* p = reinterpret_cast<const float4*>(in) + (size_t)2 * i;
  float4 a = p[0];
  float4 b = p[1];
  int lo = 0, hi = 0;
  if (E4M3) {
    lo = __builtin_amdgcn_cvt_pk_fp8_f32(a.x, a.y, lo, false);
    lo = __builtin_amdgcn_cvt_pk_fp8_f32(a.z, a.w, lo, true);
    hi = __builtin_amdgcn_cvt_pk_fp8_f32(b.x, b.y, hi, false);
    hi = __builtin_amdgcn_cvt_pk_fp8_f32(b.z, b.w, hi, true);
  } else {
    lo = __builtin_amdgcn_cvt_pk_bf8_f32(a.x, a.y, lo, false);
    lo = __builtin_amdgcn_cvt_pk_bf8_f32(a.z, a.w, lo, true);
    hi = __builtin_amdgcn_cvt_pk_bf8_f32(b.x, b.y, hi, false);
    hi = __builtin_amdgcn_cvt_pk_bf8_f32(b.z, b.w, hi, true);
  }
  out[i] = make_uint2((unsigned)lo, (unsigned)hi);
}

// ---------------------------------------------------------------------------
// FP8 B^T-GEMM, m97 structure ported to fp8 (ladder step 3-fp8):
//   C[m,n] = sum_k Aq[m,k](e5m2) * Wq[n,k](e4m3) + bias[n], fp16-rounded, f32 out
// 128x128 tile, BK=64 (fp8 bytes), 4 waves in 2x2, 16x16x32 MFMA,
// global_load_lds width-16 staging (linear LDS, wave-uniform base + lane*16).
// ---------------------------------------------------------------------------
__global__ __launch_bounds__(256) void gemm_fp8_kernel(
    const unsigned char* __restrict__ Aq,   // [M,K] e5m2
    const unsigned char* __restrict__ Wq,   // [N,K] e4m3
    const float* __restrict__ bias,         // [N] fp16-exact values in f32
    float* __restrict__ C)                  // [M,N] f32 (fp16-rounded values)
{
  constexpr int BK = 64;
  __shared__ unsigned char sA[128 * BK];    // 8 KiB
  __shared__ unsigned char sB[128 * BK];    // 8 KiB

  const int tid  = threadIdx.x;
  const int lane = tid & 63;
  const int wave = tid >> 6;
  const int wr   = wave >> 1;               // wave row (0..1) -> 64 rows each
  const int wc   = wave & 1;                // wave col (0..1) -> 64 cols each

  const int bm = blockIdx.y * 128;
  const int bn = blockIdx.x * 128;

  f32x4 acc[4][4] = {};

  // Staging geometry: 128 rows x 64B = 8 KiB per tile = 2 insts x 256 thr x 16B.
  // Linear byte offset for inst i: i*4096 + wave*1024 + lane*16.
  const int lin0 = wave * 1024 + lane * 16;
  const int lin1 = 4096 + wave * 1024 + lane * 16;
  const unsigned char* gA0 = Aq + (size_t)(bm + (lin0 >> 6)) * K_DIM + (lin0 & 63);
  const unsigned char* gA1 = Aq + (size_t)(bm + (lin1 >> 6)) * K_DIM + (lin1 & 63);
  const unsigned char* gB0 = Wq + (size_t)(bn + (lin0 >> 6)) * K_DIM + (lin0 & 63);
  const unsigned char* gB1 = Wq + (size_t)(bn + (lin1 >> 6)) * K_DIM + (lin1 & 63);

  for (int kt = 0; kt < K_DIM / BK; ++kt) {
    const int k0 = kt * BK;
    __builtin_amdgcn_global_load_lds(
        (const __attribute__((address_space(1))) void*)(gA0 + k0),
        (__attribute__((address_space(3))) void*)(sA + wave * 1024), 16, 0, 0);
    __builtin_amdgcn_global_load_lds(
        (const __attribute__((address_space(1))) void*)(gA1 + k0),
        (__attribute__((address_space(3))) void*)(sA + 4096 + wave * 1024), 16, 0, 0);
    __builtin_amdgcn_global_load_lds(
        (const __attribute__((address_space(1))) void*)(gB0 + k0),
        (__attribute__((address_space(3))) void*)(sB + wave * 1024), 16, 0, 0);
    __builtin_amdgcn_global_load_lds(
        (const __attribute__((address_space(1))) void*)(gB1 + k0),
        (__attribute__((address_space(3))) void*)(sB + 4096 + wave * 1024), 16, 0, 0);
    __syncthreads();   // drains vmcnt before any lane reads LDS

    #pragma unroll
    for (int ks = 0; ks < 2; ++ks) {
      const int kb = ks * 32 + (lane >> 4) * 8;   // 8 contiguous fp8 per lane
      long av[4], bv[4];
      #pragma unroll
      for (int m = 0; m < 4; ++m) {
        const int r = wr * 64 + m * 16 + (lane & 15);
        av[m] = *reinterpret_cast<const long*>(sA + r * BK + kb);
      }
      #pragma unroll
      for (int n = 0; n < 4; ++n) {
        const int r = wc * 64 + n * 16 + (lane & 15);
        bv[n] = *reinterpret_cast<const long*>(sB + r * BK + kb);
      }
      #pragma unroll
      for (int m = 0; m < 4; ++m)
        #pragma unroll
        for (int n = 0; n < 4; ++n)
          acc[m][n] = __builtin_amdgcn_mfma_f32_16x16x32_bf8_fp8(
              av[m], bv[n], acc[m][n], 0, 0, 0);
    }
    __syncthreads();   // before next K-step overwrites the tiles
  }

  // Epilogue: +bias (f32), round through fp16 (matches reference .astype(f16)),
  // store widened to f32. C/D layout: col = lane&15, row = (lane>>4)*4 + j.
  #pragma unroll
  for (int n = 0; n < 4; ++n) {
    const int col = bn + wc * 64 + n * 16 + (lane & 15);
    const float bv = bias[col];
    #pragma unroll
    for (int m = 0; m < 4; ++m) {
      const int row0 = bm + wr * 64 + m * 16 + ((lane >> 4) << 2);
      #pragma unroll
      for (int j = 0; j < 4; ++j) {
        C[(size_t)(row0 + j) * N_DIM + col] =
            __half2float(__float2half_rn(acc[m][n][j] + bv));
      }
    }
  }
}

// ---------------------------------------------------------------------------
extern "C" void kernel_launch(void* const* d_in, const int* in_sizes, int n_in,
                              void* d_out, int out_size, void* d_ws, size_t ws_size,
                              hipStream_t stream) {
  const float* x  = (const float*)d_in[0];   // [B,S,DIN] fp16-exact values in f32
  const float* w  = (const float*)d_in[1];   // [DOUT,DIN]
  const float* bs = (const float*)d_in[2];   // [DOUT]
  float* out = (float*)d_out;

  // Workspace: xq = 64 MiB e5m2, wq = 16 MiB e4m3 (needs 80 MiB of d_ws)
  unsigned char* xq = (unsigned char*)d_ws;
  unsigned char* wq = (unsigned char*)d_ws + (size_t)M_DIM * K_DIM;

  const int n8x = (M_DIM * K_DIM) / 8;   // 8,388,608
  const int n8w = (N_DIM * K_DIM) / 8;   // 2,097,152
  quant_kernel<false><<<n8x / 256, 256, 0, stream>>>(x, (uint2*)xq, n8x);
  quant_kernel<true ><<<n8w / 256, 256, 0, stream>>>(w, (uint2*)wq, n8w);

  dim3 grid(N_DIM / 128, M_DIM / 128);   // (32, 128) = 4096 blocks
  gemm_fp8_kernel<<<grid, 256, 0, stream>>>(xq, wq, bs, out);
}

// Round 2
// 609.481 us; speedup vs baseline: 2.0839x; 2.0839x over previous
//
#include <hip/hip_runtime.h>
#include <hip/hip_fp16.h>

// Problem constants (fixed by the reference file)
#define M_DIM 16384   // B*S = 4*4096
#define N_DIM 4096    // DOUT
#define K_DIM 4096    // DIN

typedef __attribute__((ext_vector_type(4))) float f32x4;
typedef __attribute__((ext_vector_type(2))) long  i64x2;

// ---------------------------------------------------------------------------
// Quantize fp32 (fp16-exact values) -> fp8 with RNE, emitting a FRAGMENT-ORDER
// TILED layout so the GEMM's LDS reads are conflict-free:
//   out is [nrow/128][K/64] tiles of 8192 bytes.
//   Within a tile, byte p = mb*1024 + l*16 + ks*8 + b  (mb 0..7, l 0..63,
//   ks 0..1, b 0..7) holds element
//     row = tile_r*128 + mb*16 + (l&15)
//     k   = tile_k*64  + ks*32 + (l>>4)*8 + b
//   which is exactly the (verified) A/B fragment layout of
//   v_mfma_f32_16x16x32_bf8_fp8 with lane l reading ds_read_b128 at
//   mb*1024 + l*16 (two K-slices per read).
// E4M3=true -> OCP e4m3fn (weight); false -> OCP e5m2 (activations).
// One thread per 8-byte output group: 32B coalesced-ish read, 8B coalesced write.
// ---------------------------------------------------------------------------
template<bool E4M3>
__global__ __launch_bounds__(256) void quant_tile_kernel(
    const float* __restrict__ in,   // [R, K_DIM] row-major f32
    uint2* __restrict__ out,        // tiled fp8 bytes, R*K_DIM total (as uint2 pairs? no: 8B groups)
    int ngrp)                       // R*K_DIM/8
{
  int t = blockIdx.x * 256 + threadIdx.x;
  if (t >= ngrp) return;
  const int gin  = t & 1023;        // 8-byte group within 8 KiB tile
  const int tile = t >> 10;
  const int kt   = tile & 63;       // K/64 = 64 K-tiles
  const int bt   = tile >> 6;       // row-block (128 rows)
  const int mb   = gin >> 7;        // 16-row sub-block
  const int q    = gin & 127;       // l*2 + ks
  const int l    = q >> 1;
  const int ks   = q & 1;
  const int row  = bt * 128 + mb * 16 + (l & 15);
  const int k    = kt * 64 + ks * 32 + (l >> 4) * 8;

  const float4* p = reinterpret_cast<const float4*>(in + (size_t)row * K_DIM + k);
  float4 a = p[0];
  float4 b = p[1];
  int lo = 0, hi = 0;
  if (E4M3) {
    lo = __builtin_amdgcn_cvt_pk_fp8_f32(a.x, a.y, lo, false);
    lo = __builtin_amdgcn_cvt_pk_fp8_f32(a.z, a.w, lo, true);
    hi = __builtin_amdgcn_cvt_pk_fp8_f32(b.x, b.y, hi, false);
    hi = __builtin_amdgcn_cvt_pk_fp8_f32(b.z, b.w, hi, true);
  } else {
    lo = __builtin_amdgcn_cvt_pk_bf8_f32(a.x, a.y, lo, false);
    lo = __builtin_amdgcn_cvt_pk_bf8_f32(a.z, a.w, lo, true);
    hi = __builtin_amdgcn_cvt_pk_bf8_f32(b.x, b.y, hi, false);
    hi = __builtin_amdgcn_cvt_pk_bf8_f32(b.z, b.w, hi, true);
  }
  out[t] = make_uint2((unsigned)lo, (unsigned)hi);
}

// ---------------------------------------------------------------------------
// FP8 B^T-GEMM on pre-tiled inputs. 128x128 tile, BK=64 fp8, 4 waves (2x2),
// v_mfma_f32_16x16x32_bf8_fp8 (A=e5m2 activations, B=e4m3 weight).
// Staging: tiles are contiguous 8 KiB in fragment order -> global_load_lds
// width-16 with identical linear global/LDS offsets.
// Fragment read: one ds_read_b128 per (row-block) -> zero bank conflicts.
// ---------------------------------------------------------------------------
__global__ __launch_bounds__(256) void gemm_fp8_kernel(
    const unsigned char* __restrict__ Aq,   // tiled [128][64][8192] e5m2
    const unsigned char* __restrict__ Wq,   // tiled [32][64][8192] e4m3
    const float* __restrict__ bias,         // [N] fp16-exact values in f32
    float* __restrict__ C)                  // [M,N] f32 (fp16-rounded values)
{
  __shared__ __align__(16) unsigned char sA[8192];
  __shared__ __align__(16) unsigned char sB[8192];

  const int tid  = threadIdx.x;
  const int lane = tid & 63;
  const int wave = tid >> 6;
  const int wr   = wave >> 1;               // wave row (0..1) -> 64 rows
  const int wc   = wave & 1;                // wave col (0..1) -> 64 cols

  const int bmi = blockIdx.y;               // 0..127
  const int bni = blockIdx.x;               // 0..31

  const unsigned char* tA = Aq + (size_t)bmi * 64 * 8192;
  const unsigned char* tB = Wq + (size_t)bni * 64 * 8192;

  f32x4 acc[4][4] = {};

  const int soff  = wave * 1024 + lane * 16;   // shared global/LDS staging offset

  for (int kt = 0; kt < 64; ++kt) {
    const unsigned char* gA = tA + (size_t)kt * 8192;
    const unsigned char* gB = tB + (size_t)kt * 8192;
    __builtin_amdgcn_global_load_lds(
        (const __attribute__((address_space(1))) void*)(gA + soff),
        (__attribute__((address_space(3))) void*)(sA + wave * 1024), 16, 0, 0);
    __builtin_amdgcn_global_load_lds(
        (const __attribute__((address_space(1))) void*)(gA + 4096 + soff),
        (__attribute__((address_space(3))) void*)(sA + 4096 + wave * 1024), 16, 0, 0);
    __builtin_amdgcn_global_load_lds(
        (const __attribute__((address_space(1))) void*)(gB + soff),
        (__attribute__((address_space(3))) void*)(sB + wave * 1024), 16, 0, 0);
    __builtin_amdgcn_global_load_lds(
        (const __attribute__((address_space(1))) void*)(gB + 4096 + soff),
        (__attribute__((address_space(3))) void*)(sB + 4096 + wave * 1024), 16, 0, 0);
    __syncthreads();   // drains vmcnt before any lane reads LDS

    i64x2 av[4], bv[4];
    #pragma unroll
    for (int m = 0; m < 4; ++m)
      av[m] = *reinterpret_cast<const i64x2*>(sA + (wr * 4 + m) * 1024 + lane * 16);
    #pragma unroll
    for (int n = 0; n < 4; ++n)
      bv[n] = *reinterpret_cast<const i64x2*>(sB + (wc * 4 + n) * 1024 + lane * 16);

    #pragma unroll
    for (int m = 0; m < 4; ++m)
      #pragma unroll
      for (int n = 0; n < 4; ++n) {
        acc[m][n] = __builtin_amdgcn_mfma_f32_16x16x32_bf8_fp8(
            av[m][0], bv[n][0], acc[m][n], 0, 0, 0);
        acc[m][n] = __builtin_amdgcn_mfma_f32_16x16x32_bf8_fp8(
            av[m][1], bv[n][1], acc[m][n], 0, 0, 0);
      }

    __syncthreads();   // before next K-step overwrites the tiles
  }

  // Epilogue: +bias (f32), round through fp16 (matches reference .astype(f16)),
  // store widened to f32. C/D layout: col = lane&15, row = (lane>>4)*4 + j.
  #pragma unroll
  for (int n = 0; n < 4; ++n) {
    const int col = bni * 128 + wc * 64 + n * 16 + (lane & 15);
    const float bv = bias[col];
    #pragma unroll
    for (int m = 0; m < 4; ++m) {
      const int row0 = bmi * 128 + wr * 64 + m * 16 + ((lane >> 4) << 2);
      #pragma unroll
      for (int j = 0; j < 4; ++j) {
        C[(size_t)(row0 + j) * N_DIM + col] =
            __half2float(__float2half_rn(acc[m][n][j] + bv));
      }
    }
  }
}

// ---------------------------------------------------------------------------
extern "C" void kernel_launch(void* const* d_in, const int* in_sizes, int n_in,
                              void* d_out, int out_size, void* d_ws, size_t ws_size,
                              hipStream_t stream) {
  const float* x  = (const float*)d_in[0];   // [B,S,DIN] fp16-exact values in f32
  const float* w  = (const float*)d_in[1];   // [DOUT,DIN]
  const float* bs = (const float*)d_in[2];   // [DOUT]
  float* out = (float*)d_out;

  // Workspace: xq = 64 MiB e5m2 (tiled), wq = 16 MiB e4m3 (tiled)
  unsigned char* xq = (unsigned char*)d_ws;
  unsigned char* wq = (unsigned char*)d_ws + (size_t)M_DIM * K_DIM;

  const int ngx = (M_DIM * K_DIM) / 8;   // 8,388,608 groups
  const int ngw = (N_DIM * K_DIM) / 8;   // 2,097,152 groups
  quant_tile_kernel<false><<<ngx / 256, 256, 0, stream>>>(x, (uint2*)xq, ngx);
  quant_tile_kernel<true ><<<ngw / 256, 256, 0, stream>>>(w, (uint2*)wq, ngw);

  dim3 grid(N_DIM / 128, M_DIM / 128);   // (32, 128) = 4096 blocks
  gemm_fp8_kernel<<<grid, 256, 0, stream>>>(xq, wq, bs, out);
}

// Round 3
// 543.267 us; speedup vs baseline: 2.3379x; 1.1219x over previous
//
#include <hip/hip_runtime.h>
#include <hip/hip_fp16.h>

// Problem constants (fixed by the reference file)
#define M_DIM 16384   // B*S = 4*4096
#define N_DIM 4096    // DOUT
#define K_DIM 4096    // DIN

typedef __attribute__((ext_vector_type(4)))  float f32x16_4;
typedef __attribute__((ext_vector_type(16))) float f32x16;
typedef __attribute__((ext_vector_type(4)))  int   i32x4;
typedef __attribute__((ext_vector_type(8)))  int   i32x8;

// ---------------------------------------------------------------------------
// Quantize fp32 (fp16-exact values) -> fp8 RNE, emitting the 32x32x64 MFMA
// fragment-order tiled layout:
//   out = [nrow/128][K/64] tiles of 8192 B.
//   tile byte p = sb*2048 + half*1024 + l*16 + b   (sb 0..3, half 0..1,
//   l 0..63, b 0..15) holds element
//     row = tile_r*128 + sb*32 + (l&31)
//     k   = tile_k*64  + (l>>5)*32 + half*16 + b
//   so lane l of the GEMM reads its v_mfma_f32_32x32x64_f8f6f4 fragment as
//   two stride-16-contiguous ds_read_b128 (base, base+1024) -> 0 conflicts,
//   regs 0-3 = k 0..15, regs 4-7 = k 16..31 of its 32-k slice.
// E4M3=true -> OCP e4m3fn (weight); false -> OCP e5m2 (activations).
// One thread per 16 output bytes: 64B read, 16B coalesced write.
// ---------------------------------------------------------------------------
template<bool E4M3>
__global__ __launch_bounds__(256) void quant_tile_kernel(
    const float* __restrict__ in,   // [R, K_DIM] row-major f32
    uint4* __restrict__ out,        // tiled fp8 bytes, R*K_DIM/16 groups
    int ngrp)
{
  int t = blockIdx.x * 256 + threadIdx.x;
  if (t >= ngrp) return;
  const int g    = t & 511;         // 16-byte group within 8 KiB tile
  const int tile = t >> 9;
  const int kt   = tile & 63;       // K/64 = 64 K-tiles
  const int bt   = tile >> 6;       // 128-row block
  const int sb   = g >> 7;          // 32-row sub-block
  const int half = (g >> 6) & 1;
  const int l    = g & 63;
  const int row  = bt * 128 + sb * 32 + (l & 31);
  const int k    = kt * 64 + (l >> 5) * 32 + half * 16;

  const float4* p = reinterpret_cast<const float4*>(in + (size_t)row * K_DIM + k);
  float4 v0 = p[0], v1 = p[1], v2 = p[2], v3 = p[3];
  int w0 = 0, w1 = 0, w2 = 0, w3 = 0;
  if (E4M3) {
    w0 = __builtin_amdgcn_cvt_pk_fp8_f32(v0.x, v0.y, w0, false);
    w0 = __builtin_amdgcn_cvt_pk_fp8_f32(v0.z, v0.w, w0, true);
    w1 = __builtin_amdgcn_cvt_pk_fp8_f32(v1.x, v1.y, w1, false);
    w1 = __builtin_amdgcn_cvt_pk_fp8_f32(v1.z, v1.w, w1, true);
    w2 = __builtin_amdgcn_cvt_pk_fp8_f32(v2.x, v2.y, w2, false);
    w2 = __builtin_amdgcn_cvt_pk_fp8_f32(v2.z, v2.w, w2, true);
    w3 = __builtin_amdgcn_cvt_pk_fp8_f32(v3.x, v3.y, w3, false);
    w3 = __builtin_amdgcn_cvt_pk_fp8_f32(v3.z, v3.w, w3, true);
  } else {
    w0 = __builtin_amdgcn_cvt_pk_bf8_f32(v0.x, v0.y, w0, false);
    w0 = __builtin_amdgcn_cvt_pk_bf8_f32(v0.z, v0.w, w0, true);
    w1 = __builtin_amdgcn_cvt_pk_bf8_f32(v1.x, v1.y, w1, false);
    w1 = __builtin_amdgcn_cvt_pk_bf8_f32(v1.z, v1.w, w1, true);
    w2 = __builtin_amdgcn_cvt_pk_bf8_f32(v2.x, v2.y, w2, false);
    w2 = __builtin_amdgcn_cvt_pk_bf8_f32(v2.z, v2.w, w2, true);
    w3 = __builtin_amdgcn_cvt_pk_bf8_f32(v3.x, v3.y, w3, false);
    w3 = __builtin_amdgcn_cvt_pk_bf8_f32(v3.z, v3.w, w3, true);
  }
  out[t] = make_uint4((unsigned)w0, (unsigned)w1, (unsigned)w2, (unsigned)w3);
}

// ---------------------------------------------------------------------------
// FP8 MX-scaled B^T-GEMM on pre-tiled inputs. 128x128 tile, BK=64, 4 waves
// (2x2, each owns 64x64 = 2x2 MFMAs of 32x32x64).
// v_mfma_f32_32x32x64_f8f6f4, cbsz=1 (A bf8/e5m2), blgp=0 (B fp8/e4m3),
// unit E8M0 scales (0x7F -> 1.0) => numerically identical to plain fp8 GEMM
// at 2x the MFMA rate.
// Staging: linear global_load_lds width-16 (tiles already in fragment order).
// ---------------------------------------------------------------------------
__global__ __launch_bounds__(256) void gemm_fp8_kernel(
    const unsigned char* __restrict__ Aq,   // tiled [128][64][8192] e5m2
    const unsigned char* __restrict__ Wq,   // tiled [32][64][8192] e4m3
    const float* __restrict__ bias,         // [N] fp16-exact values in f32
    float* __restrict__ C)                  // [M,N] f32 (fp16-rounded values)
{
  __shared__ __align__(16) unsigned char sA[8192];
  __shared__ __align__(16) unsigned char sB[8192];

  const int tid  = threadIdx.x;
  const int lane = tid & 63;
  const int wave = tid >> 6;
  const int wr   = wave >> 1;               // wave row (0..1) -> 64 rows
  const int wc   = wave & 1;                // wave col (0..1) -> 64 cols

  const int bmi = blockIdx.y;               // 0..127
  const int bni = blockIdx.x;               // 0..31

  const unsigned char* tA = Aq + (size_t)bmi * 64 * 8192;
  const unsigned char* tB = Wq + (size_t)bni * 64 * 8192;

  f32x16 acc[2][2] = {};

  const int soff = wave * 1024 + lane * 16;   // linear staging offset

  for (int kt = 0; kt < 64; ++kt) {
    const unsigned char* gA = tA + (size_t)kt * 8192;
    const unsigned char* gB = tB + (size_t)kt * 8192;
    __builtin_amdgcn_global_load_lds(
        (const __attribute__((address_space(1))) void*)(gA + soff),
        (__attribute__((address_space(3))) void*)(sA + wave * 1024), 16, 0, 0);
    __builtin_amdgcn_global_load_lds(
        (const __attribute__((address_space(1))) void*)(gA + 4096 + soff),
        (__attribute__((address_space(3))) void*)(sA + 4096 + wave * 1024), 16, 0, 0);
    __builtin_amdgcn_global_load_lds(
        (const __attribute__((address_space(1))) void*)(gB + soff),
        (__attribute__((address_space(3))) void*)(sB + wave * 1024), 16, 0, 0);
    __builtin_amdgcn_global_load_lds(
        (const __attribute__((address_space(1))) void*)(gB + 4096 + soff),
        (__attribute__((address_space(3))) void*)(sB + 4096 + wave * 1024), 16, 0, 0);
    __syncthreads();   // drains vmcnt before any lane reads LDS

    i32x8 av[2], bv[2];
    #pragma unroll
    for (int m = 0; m < 2; ++m) {
      const unsigned char* base = sA + (wr * 2 + m) * 2048 + lane * 16;
      i32x4 lo = *reinterpret_cast<const i32x4*>(base);
      i32x4 hi = *reinterpret_cast<const i32x4*>(base + 1024);
      av[m] = i32x8{lo.x, lo.y, lo.z, lo.w, hi.x, hi.y, hi.z, hi.w};
    }
    #pragma unroll
    for (int n = 0; n < 2; ++n) {
      const unsigned char* base = sB + (wc * 2 + n) * 2048 + lane * 16;
      i32x4 lo = *reinterpret_cast<const i32x4*>(base);
      i32x4 hi = *reinterpret_cast<const i32x4*>(base + 1024);
      bv[n] = i32x8{lo.x, lo.y, lo.z, lo.w, hi.x, hi.y, hi.z, hi.w};
    }

    #pragma unroll
    for (int m = 0; m < 2; ++m)
      #pragma unroll
      for (int n = 0; n < 2; ++n)
        acc[m][n] = __builtin_amdgcn_mfma_scale_f32_32x32x64_f8f6f4(
            av[m], bv[n], acc[m][n],
            1 /*cbsz: A = bf8 e5m2*/, 0 /*blgp: B = fp8 e4m3*/,
            0, 0x7F7F7F7F /*scale_a = 1.0*/,
            0, 0x7F7F7F7F /*scale_b = 1.0*/);

    __syncthreads();   // before next K-step overwrites the tiles
  }

  // Epilogue: +bias (f32), round through fp16 (matches reference .astype(f16)),
  // store widened to f32.
  // 32x32 C/D layout (verified, shape-determined): col = lane&31,
  // row = (reg&3) + 8*(reg>>2) + 4*(lane>>5).
  #pragma unroll
  for (int n = 0; n < 2; ++n) {
    const int col = bni * 128 + wc * 64 + n * 32 + (lane & 31);
    const float bv = bias[col];
    #pragma unroll
    for (int m = 0; m < 2; ++m) {
      const int rbase = bmi * 128 + wr * 64 + m * 32 + ((lane >> 5) << 2);
      #pragma unroll
      for (int r = 0; r < 16; ++r) {
        const int row = rbase + (r & 3) + 8 * (r >> 2);
        C[(size_t)row * N_DIM + col] =
            __half2float(__float2half_rn(acc[m][n][r] + bv));
      }
    }
  }
}

// ---------------------------------------------------------------------------
extern "C" void kernel_launch(void* const* d_in, const int* in_sizes, int n_in,
                              void* d_out, int out_size, void* d_ws, size_t ws_size,
                              hipStream_t stream) {
  const float* x  = (const float*)d_in[0];   // [B,S,DIN] fp16-exact values in f32
  const float* w  = (const float*)d_in[1];   // [DOUT,DIN]
  const float* bs = (const float*)d_in[2];   // [DOUT]
  float* out = (float*)d_out;

  // Workspace: xq = 64 MiB e5m2 (tiled), wq = 16 MiB e4m3 (tiled)
  unsigned char* xq = (unsigned char*)d_ws;
  unsigned char* wq = (unsigned char*)d_ws + (size_t)M_DIM * K_DIM;

  const int ngx = (M_DIM * K_DIM) / 16;   // 4,194,304 groups
  const int ngw = (N_DIM * K_DIM) / 16;   // 1,048,576 groups
  quant_tile_kernel<false><<<ngx / 256, 256, 0, stream>>>(x, (uint4*)xq, ngx);
  quant_tile_kernel<true ><<<ngw / 256, 256, 0, stream>>>(w, (uint4*)wq, ngw);

  dim3 grid(N_DIM / 128, M_DIM / 128);   // (32, 128) = 4096 blocks
  gemm_fp8_kernel<<<grid, 256, 0, stream>>>(xq, wq, bs, out);
}

// Round 4
// 356.576 us; speedup vs baseline: 3.5619x; 1.5236x over previous
//
#include <hip/hip_runtime.h>
#include <hip/hip_fp16.h>

// Problem constants (fixed by the reference file)
#define M_DIM 16384   // B*S = 4*4096
#define N_DIM 4096    // DOUT
#define K_DIM 4096    // DIN

typedef __attribute__((ext_vector_type(16))) float f32x16;
typedef __attribute__((ext_vector_type(4)))  int   i32x4;
typedef __attribute__((ext_vector_type(8)))  int   i32x8;

// ---------------------------------------------------------------------------
// Quantize fp32 (fp16-exact values) -> fp8 RNE, emitting the 32x32x64 MFMA
// fragment-order tiled layout for 256-row blocks:
//   out = [nrow/256][K/64] tiles of 16384 B.
//   tile byte p = sb*2048 + half*1024 + l*16 + b   (sb 0..7, half 0..1,
//   l 0..63, b 0..15) holds element
//     row = tile_r*256 + sb*32 + (l&31)
//     k   = tile_k*64  + (l>>5)*32 + half*16 + b
//   (verified round-3 mapping, sb widened 4->8) so GEMM lane l reads its
//   v_mfma_f32_32x32x64_f8f6f4 fragment as two contiguous ds_read_b128
//   (base, base+1024) -> 0 bank conflicts; staging is linear.
// E4M3=true -> OCP e4m3fn (weight); false -> OCP e5m2 (activations).
// ---------------------------------------------------------------------------
template<bool E4M3>
__global__ __launch_bounds__(256) void quant_tile_kernel(
    const float* __restrict__ in,   // [R, K_DIM] row-major f32
    uint4* __restrict__ out,        // tiled fp8 bytes, R*K_DIM/16 groups
    int ngrp)
{
  int t = blockIdx.x * 256 + threadIdx.x;
  if (t >= ngrp) return;
  const int g    = t & 1023;        // 16-byte group within 16 KiB tile
  const int tile = t >> 10;
  const int kt   = tile & 63;       // K/64 = 64 K-tiles
  const int bt   = tile >> 6;       // 256-row block
  const int sb   = g >> 7;          // 32-row sub-block (0..7)
  const int half = (g >> 6) & 1;
  const int l    = g & 63;
  const int row  = bt * 256 + sb * 32 + (l & 31);
  const int k    = kt * 64 + (l >> 5) * 32 + half * 16;

  const float4* p = reinterpret_cast<const float4*>(in + (size_t)row * K_DIM + k);
  float4 v0 = p[0], v1 = p[1], v2 = p[2], v3 = p[3];
  int w0 = 0, w1 = 0, w2 = 0, w3 = 0;
  if (E4M3) {
    w0 = __builtin_amdgcn_cvt_pk_fp8_f32(v0.x, v0.y, w0, false);
    w0 = __builtin_amdgcn_cvt_pk_fp8_f32(v0.z, v0.w, w0, true);
    w1 = __builtin_amdgcn_cvt_pk_fp8_f32(v1.x, v1.y, w1, false);
    w1 = __builtin_amdgcn_cvt_pk_fp8_f32(v1.z, v1.w, w1, true);
    w2 = __builtin_amdgcn_cvt_pk_fp8_f32(v2.x, v2.y, w2, false);
    w2 = __builtin_amdgcn_cvt_pk_fp8_f32(v2.z, v2.w, w2, true);
    w3 = __builtin_amdgcn_cvt_pk_fp8_f32(v3.x, v3.y, w3, false);
    w3 = __builtin_amdgcn_cvt_pk_fp8_f32(v3.z, v3.w, w3, true);
  } else {
    w0 = __builtin_amdgcn_cvt_pk_bf8_f32(v0.x, v0.y, w0, false);
    w0 = __builtin_amdgcn_cvt_pk_bf8_f32(v0.z, v0.w, w0, true);
    w1 = __builtin_amdgcn_cvt_pk_bf8_f32(v1.x, v1.y, w1, false);
    w1 = __builtin_amdgcn_cvt_pk_bf8_f32(v1.z, v1.w, w1, true);
    w2 = __builtin_amdgcn_cvt_pk_bf8_f32(v2.x, v2.y, w2, false);
    w2 = __builtin_amdgcn_cvt_pk_bf8_f32(v2.z, v2.w, w2, true);
    w3 = __builtin_amdgcn_cvt_pk_bf8_f32(v3.x, v3.y, w3, false);
    w3 = __builtin_amdgcn_cvt_pk_bf8_f32(v3.z, v3.w, w3, true);
  }
  out[t] = make_uint4((unsigned)w0, (unsigned)w1, (unsigned)w2, (unsigned)w3);
}

// ---------------------------------------------------------------------------
// Deep-pipelined MX-fp8 GEMM (T1+T3+T4+T5): 256x256 tile, BK=64, 8 waves
// (2 M x 4 N), per-wave 128x64 output = acc[4][2] of f32x16.
// LDS: 2 x {A 16KB | B 16KB} double buffer = 64 KiB.
// Per K-tile: 2 phases x {8/4 ds_read_b128, barrier, lgkmcnt(0), 4 MFMA,
// barrier}, prefetch of tile kt+2 issued right after the barrier that
// proves its LDS region was fully consumed. vmcnt(4) once per K-tile
// (2 tiles / 8 loads per thread in flight, never drained to 0).
// ---------------------------------------------------------------------------
__global__ __launch_bounds__(512, 2) void gemm_fp8_kernel(
    const unsigned char* __restrict__ Aq,   // tiled [64][64][16384] e5m2
    const unsigned char* __restrict__ Wq,   // tiled [16][64][16384] e4m3
    const float* __restrict__ bias,         // [N] fp16-exact values in f32
    float* __restrict__ C)                  // [M,N] f32 (fp16-rounded values)
{
  __shared__ __align__(16) unsigned char lds[65536];   // [2][A:16K | B:16K]

  const int tid  = threadIdx.x;
  const int lane = tid & 63;
  const int wave = tid >> 6;
  const int wr   = wave >> 2;               // 0..1 -> 128 rows
  const int wc   = wave & 3;                // 0..3 -> 64 cols

  // T1: XCD-aware bijective swizzle (nwg = 1024, 1024 % 8 == 0)
  const int bid = blockIdx.x;
  const int swz = (bid & 7) * 128 + (bid >> 3);
  const int bmi = swz >> 4;                 // 0..63
  const int bni = swz & 15;                 // 0..15

  const unsigned char* tA = Aq + (size_t)bmi * 64 * 16384;  // row-panel base
  const unsigned char* tB = Wq + (size_t)bni * 64 * 16384;

  const size_t t16 = (size_t)tid * 16;      // per-lane global offset
  const int    w1k = wave * 1024;           // wave-uniform LDS offset

  // dst = wave-uniform base (hw adds lane*16); src = per-lane linear.
#define STAGE(gbase, ldsoff)                                                \
  __builtin_amdgcn_global_load_lds(                                         \
      (const __attribute__((address_space(1))) void*)((gbase) + t16),       \
      (__attribute__((address_space(3))) void*)(lds + (ldsoff) + w1k), 16, 0, 0)

  f32x16 acc[4][2] = {};

  // ---- Prologue: stage tile 0 -> buf0, tile 1 -> buf1 (order matters for vmcnt)
  STAGE(tA,              0);          // A(0) h0
  STAGE(tA + 8192,       8192);       // A(0) h1
  STAGE(tB,              16384);      // B(0) h0
  STAGE(tB + 8192,       24576);      // B(0) h1
  __builtin_amdgcn_sched_barrier(0);
  STAGE(tA + 16384,          32768);  // A(1) h0
  STAGE(tA + 16384 + 8192,   40960);  // A(1) h1
  STAGE(tB + 16384,          49152);  // B(1) h0
  STAGE(tB + 16384 + 8192,   57344);  // B(1) h1
  __builtin_amdgcn_sched_barrier(0);
  asm volatile("s_waitcnt vmcnt(4)" ::: "memory");   // tile 0 landed
  __builtin_amdgcn_s_barrier();

  for (int kt = 0; kt < 64; ++kt) {
    const int cur = kt & 1;
    const unsigned char* bufA = lds + cur * 32768;
    const unsigned char* bufB = bufA + 16384;
    const size_t tp2 = (size_t)((kt + 2) & 63) * 16384;  // clamped prefetch tile

    // ===== Phase 0: A[m0,m1] + B[n0,n1] frags, 4 MFMA =====
    i32x8 av0, av1, bv0, bv1;
    {
      const unsigned char* a0 = bufA + (wr * 4 + 0) * 2048 + lane * 16;
      const unsigned char* a1 = bufA + (wr * 4 + 1) * 2048 + lane * 16;
      const unsigned char* b0 = bufB + (wc * 2 + 0) * 2048 + lane * 16;
      const unsigned char* b1 = bufB + (wc * 2 + 1) * 2048 + lane * 16;
      i32x4 lo, hi;
      lo = *(const i32x4*)a0; hi = *(const i32x4*)(a0 + 1024);
      av0 = i32x8{lo.x, lo.y, lo.z, lo.w, hi.x, hi.y, hi.z, hi.w};
      lo = *(const i32x4*)a1; hi = *(const i32x4*)(a1 + 1024);
      av1 = i32x8{lo.x, lo.y, lo.z, lo.w, hi.x, hi.y, hi.z, hi.w};
      lo = *(const i32x4*)b0; hi = *(const i32x4*)(b0 + 1024);
      bv0 = i32x8{lo.x, lo.y, lo.z, lo.w, hi.x, hi.y, hi.z, hi.w};
      lo = *(const i32x4*)b1; hi = *(const i32x4*)(b1 + 1024);
      bv1 = i32x8{lo.x, lo.y, lo.z, lo.w, hi.x, hi.y, hi.z, hi.w};
    }
    __builtin_amdgcn_s_barrier();                          // B1
    asm volatile("s_waitcnt lgkmcnt(0)" ::: "memory");
    __builtin_amdgcn_sched_barrier(0);
    __builtin_amdgcn_s_setprio(1);
    acc[0][0] = __builtin_amdgcn_mfma_scale_f32_32x32x64_f8f6f4(
        av0, bv0, acc[0][0], 1, 0, 0, 0x7F7F7F7F, 0, 0x7F7F7F7F);
    acc[0][1] = __builtin_amdgcn_mfma_scale_f32_32x32x64_f8f6f4(
        av0, bv1, acc[0][1], 1, 0, 0, 0x7F7F7F7F, 0, 0x7F7F7F7F);
    acc[1][0] = __builtin_amdgcn_mfma_scale_f32_32x32x64_f8f6f4(
        av1, bv0, acc[1][0], 1, 0, 0, 0x7F7F7F7F, 0, 0x7F7F7F7F);
    acc[1][1] = __builtin_amdgcn_mfma_scale_f32_32x32x64_f8f6f4(
        av1, bv1, acc[1][1], 1, 0, 0, 0x7F7F7F7F, 0, 0x7F7F7F7F);
    __builtin_amdgcn_s_setprio(0);
    __builtin_amdgcn_s_barrier();                          // B2 (B-region free)
    __builtin_amdgcn_sched_barrier(0);

    // ===== Phase 1: prefetch B(kt+2) into buf[cur].B; A[m2,m3] frags, 4 MFMA
    STAGE(tB + tp2,        cur * 32768 + 16384);
    STAGE(tB + tp2 + 8192, cur * 32768 + 24576);
    i32x8 av2, av3;
    {
      const unsigned char* a2 = bufA + (wr * 4 + 2) * 2048 + lane * 16;
      const unsigned char* a3 = bufA + (wr * 4 + 3) * 2048 + lane * 16;
      i32x4 lo, hi;
      lo = *(const i32x4*)a2; hi = *(const i32x4*)(a2 + 1024);
      av2 = i32x8{lo.x, lo.y, lo.z, lo.w, hi.x, hi.y, hi.z, hi.w};
      lo = *(const i32x4*)a3; hi = *(const i32x4*)(a3 + 1024);
      av3 = i32x8{lo.x, lo.y, lo.z, lo.w, hi.x, hi.y, hi.z, hi.w};
    }
    __builtin_amdgcn_s_barrier();                          // B3
    asm volatile("s_waitcnt lgkmcnt(0)" ::: "memory");
    __builtin_amdgcn_sched_barrier(0);
    __builtin_amdgcn_s_setprio(1);
    acc[2][0] = __builtin_amdgcn_mfma_scale_f32_32x32x64_f8f6f4(
        av2, bv0, acc[2][0], 1, 0, 0, 0x7F7F7F7F, 0, 0x7F7F7F7F);
    acc[2][1] = __builtin_amdgcn_mfma_scale_f32_32x32x64_f8f6f4(
        av2, bv1, acc[2][1], 1, 0, 0, 0x7F7F7F7F, 0, 0x7F7F7F7F);
    acc[3][0] = __builtin_amdgcn_mfma_scale_f32_32x32x64_f8f6f4(
        av3, bv0, acc[3][0], 1, 0, 0, 0x7F7F7F7F, 0, 0x7F7F7F7F);
    acc[3][1] = __builtin_amdgcn_mfma_scale_f32_32x32x64_f8f6f4(
        av3, bv1, acc[3][1], 1, 0, 0, 0x7F7F7F7F, 0, 0x7F7F7F7F);
    __builtin_amdgcn_s_setprio(0);
    __builtin_amdgcn_s_barrier();                          // B4 (A-region free)
    __builtin_amdgcn_sched_barrier(0);

    // ===== Tail: prefetch A(kt+2); ensure tile kt+1 landed before next iter
    STAGE(tA + tp2,        cur * 32768);
    STAGE(tA + tp2 + 8192, cur * 32768 + 8192);
    asm volatile("s_waitcnt vmcnt(4)" ::: "memory");       // tile kt+1 ready
    __builtin_amdgcn_s_barrier();                          // B5
  }
#undef STAGE

  // Epilogue: +bias, round through fp16 (matches reference), store f32.
  // 32x32 C/D layout: col = lane&31, row = (r&3) + 8*(r>>2) + 4*(lane>>5).
  #pragma unroll
  for (int n = 0; n < 2; ++n) {
    const int col = bni * 256 + wc * 64 + n * 32 + (lane & 31);
    const float bv = bias[col];
    #pragma unroll
    for (int m = 0; m < 4; ++m) {
      const int rbase = bmi * 256 + wr * 128 + m * 32 + ((lane >> 5) << 2);
      #pragma unroll
      for (int r = 0; r < 16; ++r) {
        const int row = rbase + (r & 3) + 8 * (r >> 2);
        C[(size_t)row * N_DIM + col] =
            __half2float(__float2half_rn(acc[m][n][r] + bv));
      }
    }
  }
}

// ---------------------------------------------------------------------------
extern "C" void kernel_launch(void* const* d_in, const int* in_sizes, int n_in,
                              void* d_out, int out_size, void* d_ws, size_t ws_size,
                              hipStream_t stream) {
  const float* x  = (const float*)d_in[0];   // [B,S,DIN] fp16-exact values in f32
  const float* w  = (const float*)d_in[1];   // [DOUT,DIN]
  const float* bs = (const float*)d_in[2];   // [DOUT]
  float* out = (float*)d_out;

  // Workspace: xq = 64 MiB e5m2 (tiled), wq = 16 MiB e4m3 (tiled)
  unsigned char* xq = (unsigned char*)d_ws;
  unsigned char* wq = (unsigned char*)d_ws + (size_t)M_DIM * K_DIM;

  const int ngx = (M_DIM * K_DIM) / 16;   // 4,194,304 groups
  const int ngw = (N_DIM * K_DIM) / 16;   // 1,048,576 groups
  quant_tile_kernel<false><<<ngx / 256, 256, 0, stream>>>(x, (uint4*)xq, ngx);
  quant_tile_kernel<true ><<<ngw / 256, 256, 0, stream>>>(w, (uint4*)wq, ngw);

  gemm_fp8_kernel<<<1024, 512, 0, stream>>>(xq, wq, bs, out);
}